// Round 2
// baseline (446.188 us; speedup 1.0000x reference)
//
#include <hip/hip_runtime.h>
#include <hip/hip_bf16.h>

#define NN 128   // graph nodes N
#define ND 256   // feature dim D

typedef __attribute__((ext_vector_type(8))) short short8v;
typedef __attribute__((ext_vector_type(4))) short short4v;
typedef __attribute__((ext_vector_type(4))) float floatx4;

__device__ __forceinline__ unsigned short f2bf(float x){
  unsigned u = __float_as_uint(x);
  u += 0x7FFF + ((u >> 16) & 1);   // round-to-nearest-even
  return (unsigned short)(u >> 16);
}

// Precompute Abf[256][128] bf16: rows 0..127 = origin*adj_in ; rows 128..255 = origin^T*adj_out
__global__ void prep_A(const float* __restrict__ adj_in, const float* __restrict__ adj_out,
                       unsigned short* __restrict__ Abf){
  int idx = blockIdx.x * 256 + threadIdx.x;   // 0..32767
  int m = idx >> 7, n = idx & 127;
  float v;
  if (m < NN){
    float a = adj_in[m * NN + n];
    v = (a <= 0.f) ? a * a : a;               // origin(a)*a
  } else {
    int mm = m - NN;
    float t = adj_in[n * NN + mm];            // origin^T[mm][n] = f(adj_in[n][mm])
    float o = (t <= 0.f) ? t : 1.f;
    v = o * adj_out[mm * NN + n];
  }
  Abf[idx] = f2bf(v);
}

__global__ __launch_bounds__(512, 4) void gcn_main(
    const float* __restrict__ H, const unsigned short* __restrict__ Abf,
    const float* __restrict__ eb,  const float* __restrict__ gw,
    const float* __restrict__ bg,  const float* __restrict__ oeb,
    const float* __restrict__ ogw, const float* __restrict__ obg,
    const float* __restrict__ lw,  float* __restrict__ Out)
{
  // Ht: bf16, logically [d][n] (transposed H_b). Swizzle: short idx = d*128 + (n ^ (((d>>1)&7)<<3)).
  // Staging writes (d = 4*m16 + ..., even granularity) hit all 32 banks exactly 2x -> conflict-free.
  // MFMA-phase b128 reads: 8 lanes per 16B slot = structural floor -> conflict-free.
  __shared__ __align__(16) unsigned short Ht[ND * NN];
  __shared__ float sigS[3 * NN];   // [0..127]=sig_in, [128..255]=sig_out, [256..383]=sig_loop

  const int tid  = threadIdx.x;
  const int wave = tid >> 6;
  const int lane = tid & 63;
  const int g    = lane >> 4;
  const int m16  = lane & 15;
  const int b    = blockIdx.x;
  const float* Hb = H   + (size_t)b * NN * ND;
  float*       Ob = Out + (size_t)b * NN * ND;

  // ---- stage H_b -> Ht (bf16, transposed, swizzled) with fused gate dot-products ----
  // 16-lane group G owns rows n0..n0+3; per lane: 4 d-chunks x 4 rows of float4.
  const int G  = 4 * wave + g;     // 0..31
  const int n0 = 4 * G;
  float sacc[12];
  #pragma unroll
  for (int i = 0; i < 12; ++i) sacc[i] = 0.f;

  #pragma unroll
  for (int dq = 0; dq < 4; ++dq){
    const int d0 = 64 * dq + 4 * m16;
    const floatx4 wa = *(const floatx4*)(gw  + d0);
    const floatx4 wb = *(const floatx4*)(ogw + d0);
    const floatx4 wc = *(const floatx4*)(lw  + d0);
    floatx4 rr[4];
    #pragma unroll
    for (int ro = 0; ro < 4; ++ro)
      rr[ro] = *(const floatx4*)(Hb + (size_t)(n0 + ro) * ND + d0);
    #pragma unroll
    for (int ro = 0; ro < 4; ++ro){
      const floatx4 r = rr[ro];
      sacc[3*ro+0] += r[0]*wa[0] + r[1]*wa[1] + r[2]*wa[2] + r[3]*wa[3];
      sacc[3*ro+1] += r[0]*wb[0] + r[1]*wb[1] + r[2]*wb[2] + r[3]*wb[3];
      sacc[3*ro+2] += r[0]*wc[0] + r[1]*wc[1] + r[2]*wc[2] + r[3]*wc[3];
    }
    #pragma unroll
    for (int j = 0; j < 4; ++j){
      const int d = d0 + j;
      short4v pv;
      pv[0] = (short)f2bf(rr[0][j]);
      pv[1] = (short)f2bf(rr[1][j]);
      pv[2] = (short)f2bf(rr[2][j]);
      pv[3] = (short)f2bf(rr[3][j]);
      *(short4v*)&Ht[d * NN + (n0 ^ (((d >> 1) & 7) << 3))] = pv;  // b64, 8B-aligned
    }
  }
  // reduce 12 gate partials across the 16 lanes of this group
  #pragma unroll
  for (int m = 1; m < 16; m <<= 1){
    #pragma unroll
    for (int i = 0; i < 12; ++i) sacc[i] += __shfl_xor(sacc[i], m, 64);
  }
  if (m16 == 0){
    #pragma unroll
    for (int ro = 0; ro < 4; ++ro){
      const int n = n0 + ro;
      sigS[n]          = 1.f / (1.f + __expf(-(sacc[3*ro+0] + bg[n])));
      sigS[NN + n]     = 1.f / (1.f + __expf(-(sacc[3*ro+1] + obg[n])));
      sigS[2*NN + n]   = 1.f / (1.f + __expf(-sacc[3*ro+2]));
    }
  }
  __syncthreads();

  // ---- GEMM: C[m,d] = sum_n Abf[m,n] * H_b[n,d]; operand-swapped MFMA so the
  // D fragment holds rows=d (4 consecutive per lane), cols=m (lane&15).
  const int mrow = 16 * wave + m16;   // this lane's node index m
  const float si = sigS[mrow];
  const float so = sigS[NN + mrow];
  const float sl = sigS[2 * NN + mrow];

  const floatx4 zz = {0.f, 0.f, 0.f, 0.f};
  #pragma unroll
  for (int pass = 0; pass < 2; ++pass){
    const int dbase = 128 * pass;
    floatx4 acc1[8], acc2[8];
    #pragma unroll
    for (int i = 0; i < 8; ++i){ acc1[i] = zz; acc2[i] = zz; }

    #pragma unroll
    for (int k0 = 0; k0 < 128; k0 += 32){
      const int kk = k0 + 8 * g;
      const short8v av1 = *(const short8v*)&Abf[ mrow        * 128 + kk];
      const short8v av2 = *(const short8v*)&Abf[(128 + mrow) * 128 + kk];
      #pragma unroll
      for (int df = 0; df < 8; ++df){
        const int d = dbase + 16 * df + m16;
        const short8v hv = *(const short8v*)&Ht[d * NN + (kk ^ (((d >> 1) & 7) << 3))];
        acc1[df] = __builtin_amdgcn_mfma_f32_16x16x32_bf16(hv, av1, acc1[df], 0, 0, 0);
        acc2[df] = __builtin_amdgcn_mfma_f32_16x16x32_bf16(hv, av2, acc2[df], 0, 0, 0);
      }
    }

    // ---- epilogue: out[m, d..d+3] = relu((C1+eb)*si + (C2+oeb)*so + H*sl), all dwordx4 ----
    #pragma unroll
    for (int df = 0; df < 8; ++df){
      const int dcol = dbase + 16 * df + 4 * g;     // D rows d = dcol + r, col m = mrow
      const floatx4 ebv  = *(const floatx4*)(eb  + mrow * ND + dcol);
      const floatx4 oebv = *(const floatx4*)(oeb + mrow * ND + dcol);
      const floatx4 hv4  = *(const floatx4*)(Hb  + (size_t)mrow * ND + dcol);
      floatx4 o;
      #pragma unroll
      for (int r = 0; r < 4; ++r){
        const float v = (acc1[df][r] + ebv[r]) * si
                      + (acc2[df][r] + oebv[r]) * so
                      + hv4[r] * sl;
        o[r] = fmaxf(v, 0.f);
      }
      __builtin_nontemporal_store(o, (floatx4*)(Ob + (size_t)mrow * ND + dcol));
    }
  }
}

extern "C" void kernel_launch(void* const* d_in, const int* in_sizes, int n_in,
                              void* d_out, int out_size, void* d_ws, size_t ws_size,
                              hipStream_t stream){
  const float* H    = (const float*)d_in[0];
  const float* ain  = (const float*)d_in[1];
  const float* aout = (const float*)d_in[2];
  const float* eb   = (const float*)d_in[3];
  const float* gwp  = (const float*)d_in[4];
  const float* bgp  = (const float*)d_in[5];
  const float* oebp = (const float*)d_in[6];
  const float* ogwp = (const float*)d_in[7];
  const float* obgp = (const float*)d_in[8];
  const float* lwp  = (const float*)d_in[9];
  unsigned short* Abf = (unsigned short*)d_ws;   // 64 KB

  prep_A<<<128, 256, 0, stream>>>(ain, aout, Abf);
  gcn_main<<<4096, 512, 0, stream>>>(H, Abf, eb, gwp, bgp, oebp, ogwp, obgp, lwp,
                                     (float*)d_out);
}

// Round 3
// 373.798 us; speedup vs baseline: 1.1937x; 1.1937x over previous
//
#include <hip/hip_runtime.h>
#include <hip/hip_bf16.h>

#define NN 128   // graph nodes N
#define ND 256   // feature dim D

typedef __attribute__((ext_vector_type(8))) short short8v;
typedef __attribute__((ext_vector_type(4))) short short4v;
typedef __attribute__((ext_vector_type(4))) float floatx4;

__device__ __forceinline__ unsigned short f2bf(float x){
  unsigned u = __float_as_uint(x);
  u += 0x7FFF + ((u >> 16) & 1);   // round-to-nearest-even
  return (unsigned short)(u >> 16);
}
__device__ __forceinline__ float bf2f(unsigned short h){
  return __uint_as_float(((unsigned)h) << 16);
}

// ws layout: Abf[256][128] bf16 (rows 0..127 = origin*adj_in ; 128..255 = origin^T*adj_out),
// then WgT[8][4][16][8] bf16 gate-weight MFMA B-fragments (cols j=0:gw 1:ogw 2:lw, 3..15 zero).
__global__ void prep_A(const float* __restrict__ adj_in, const float* __restrict__ adj_out,
                       const float* __restrict__ gw, const float* __restrict__ ogw,
                       const float* __restrict__ lw, unsigned short* __restrict__ Abf){
  int idx = blockIdx.x * 256 + threadIdx.x;   // 0..36863
  if (idx < 32768){
    int m = idx >> 7, n = idx & 127;
    float v;
    if (m < NN){
      float a = adj_in[m * NN + n];
      v = (a <= 0.f) ? a * a : a;               // origin(a)*a
    } else {
      int mm = m - NN;
      float t = adj_in[n * NN + mm];            // origin^T[mm][n] = f(adj_in[n][mm])
      float o = (t <= 0.f) ? t : 1.f;
      v = o * adj_out[mm * NN + n];
    }
    Abf[idx] = f2bf(v);
  } else if (idx < 32768 + 4096){
    int t   = idx - 32768;
    int j   = t & 7, m16 = (t >> 3) & 15, g = (t >> 7) & 3, kc = t >> 9;
    int d   = kc * 32 + 8 * g + j;
    float v = (m16 == 0) ? gw[d] : (m16 == 1) ? ogw[d] : (m16 == 2) ? lw[d] : 0.f;
    Abf[idx] = f2bf(v);
  }
}

__global__ __launch_bounds__(512, 4) void gcn_main(
    const float* __restrict__ H, const unsigned short* __restrict__ Abf,
    const float* __restrict__ eb,  const float* __restrict__ bg,
    const float* __restrict__ oeb, const float* __restrict__ obg,
    float* __restrict__ Out)
{
  // Ht: bf16, logically [d][n] (transposed H_b). Swizzle: short idx = d*128 + (n ^ (((d>>1)&7)<<3)).
  __shared__ __align__(16) unsigned short Ht[ND * NN];
  __shared__ float sigS[3 * NN];   // [j*128 + n]: j=0 sig_in, 1 sig_out, 2 sig_loop

  const int tid  = threadIdx.x;
  const int wave = tid >> 6;
  const int lane = tid & 63;
  const int g    = lane >> 4;
  const int m16  = lane & 15;
  const int b    = blockIdx.x;
  const float* Hb = H   + (size_t)b * NN * ND;
  float*       Ob = Out + (size_t)b * NN * ND;
  const unsigned short* WgT = Abf + 32768;

  const int G    = 4 * wave + g;     // staging group: owns rows 4G..4G+3
  const int n0   = 4 * G;
  const int arow = 16 * wave + m16;  // gate A-row / epilogue output row m

  // ---- slab-interleaved: gate MFMA (cold HBM read of Hb) + staging (L2-hot re-read) ----
  floatx4 gacc = {0.f, 0.f, 0.f, 0.f};
  #pragma unroll
  for (int s = 0; s < 4; ++s){
    // gate part: contracts cols [64s, 64s+64) of Hb against packed gate weights
    #pragma unroll
    for (int t = 0; t < 2; ++t){
      const int k0 = 64 * s + 32 * t;
      const floatx4 f0 = *(const floatx4*)(Hb + (size_t)arow * ND + k0 + 8 * g);
      const floatx4 f1 = *(const floatx4*)(Hb + (size_t)arow * ND + k0 + 8 * g + 4);
      const short8v wv = *(const short8v*)&WgT[(((k0 >> 5) * 4 + g) * 16 + m16) * 8];
      short8v af;
      af[0] = (short)f2bf(f0[0]); af[1] = (short)f2bf(f0[1]);
      af[2] = (short)f2bf(f0[2]); af[3] = (short)f2bf(f0[3]);
      af[4] = (short)f2bf(f1[0]); af[5] = (short)f2bf(f1[1]);
      af[6] = (short)f2bf(f1[2]); af[7] = (short)f2bf(f1[3]);
      gacc = __builtin_amdgcn_mfma_f32_16x16x32_bf16(af, wv, gacc, 0, 0, 0);
    }
    // staging part: same slab, rows n0..n0+3, cols d0..d0+3
    const int d0 = 64 * s + 4 * m16;
    floatx4 rr[4];
    #pragma unroll
    for (int ro = 0; ro < 4; ++ro)
      rr[ro] = *(const floatx4*)(Hb + (size_t)(n0 + ro) * ND + d0);
    #pragma unroll
    for (int j = 0; j < 4; ++j){
      const int d = d0 + j;
      short4v pv;
      pv[0] = (short)f2bf(rr[0][j]);
      pv[1] = (short)f2bf(rr[1][j]);
      pv[2] = (short)f2bf(rr[2][j]);
      pv[3] = (short)f2bf(rr[3][j]);
      *(short4v*)&Ht[d * NN + (n0 ^ (((d >> 1) & 7) << 3))] = pv;  // b64, 8B-aligned
    }
  }
  // finalize gates: D[row=4g+r][col=m16]: gate j=m16 for node n=16*wave+4g+r
  if (m16 < 3){
    #pragma unroll
    for (int r = 0; r < 4; ++r){
      const int n = 16 * wave + 4 * g + r;
      float x = gacc[r];
      if (m16 == 0)      x += bg[n];
      else if (m16 == 1) x += obg[n];
      sigS[m16 * NN + n] = 1.f / (1.f + __expf(-x));
    }
  }
  __syncthreads();

  // ---- GEMM: operand-swapped MFMA; D fragment rows=d (4 consecutive per lane), cols=m=arow
  const float si = sigS[arow];
  const float so = sigS[NN + arow];
  const float sl = sigS[2 * NN + arow];

  const floatx4 zz = {0.f, 0.f, 0.f, 0.f};
  #pragma unroll
  for (int pass = 0; pass < 2; ++pass){
    const int dbase = 128 * pass;
    floatx4 acc1[8], acc2[8];
    #pragma unroll
    for (int i = 0; i < 8; ++i){ acc1[i] = zz; acc2[i] = zz; }

    #pragma unroll
    for (int k0 = 0; k0 < 128; k0 += 32){
      const int kk = k0 + 8 * g;
      const short8v av1 = *(const short8v*)&Abf[ arow        * 128 + kk];
      const short8v av2 = *(const short8v*)&Abf[(128 + arow) * 128 + kk];
      #pragma unroll
      for (int df = 0; df < 8; ++df){
        const int d = dbase + 16 * df + m16;
        const short8v hv = *(const short8v*)&Ht[d * NN + (kk ^ (((d >> 1) & 7) << 3))];
        acc1[df] = __builtin_amdgcn_mfma_f32_16x16x32_bf16(hv, av1, acc1[df], 0, 0, 0);
        acc2[df] = __builtin_amdgcn_mfma_f32_16x16x32_bf16(hv, av2, acc2[df], 0, 0, 0);
      }
    }

    // ---- epilogue: out[m, d..d+3] = relu((C1+eb)*si + (C2+oeb)*so + H*sl) ----
    #pragma unroll
    for (int df = 0; df < 8; ++df){
      const int dcol = dbase + 16 * df + 4 * g;     // D rows d = dcol + r, col m = arow
      const floatx4 ebv  = *(const floatx4*)(eb  + arow * ND + dcol);
      const floatx4 oebv = *(const floatx4*)(oeb + arow * ND + dcol);
      float hl[4];
      #pragma unroll
      for (int r = 0; r < 4; ++r){
        const int d = dcol + r;
        hl[r] = bf2f(Ht[d * NN + (arow ^ (((d >> 1) & 7) << 3))]);  // H[arow][d] from LDS
      }
      floatx4 o;
      #pragma unroll
      for (int r = 0; r < 4; ++r){
        const float v = (acc1[df][r] + ebv[r]) * si
                      + (acc2[df][r] + oebv[r]) * so
                      + hl[r] * sl;
        o[r] = fmaxf(v, 0.f);
      }
      __builtin_nontemporal_store(o, (floatx4*)(Ob + (size_t)arow * ND + dcol));
    }
  }
}

extern "C" void kernel_launch(void* const* d_in, const int* in_sizes, int n_in,
                              void* d_out, int out_size, void* d_ws, size_t ws_size,
                              hipStream_t stream){
  const float* H    = (const float*)d_in[0];
  const float* ain  = (const float*)d_in[1];
  const float* aout = (const float*)d_in[2];
  const float* eb   = (const float*)d_in[3];
  const float* gwp  = (const float*)d_in[4];
  const float* bgp  = (const float*)d_in[5];
  const float* oebp = (const float*)d_in[6];
  const float* ogwp = (const float*)d_in[7];
  const float* obgp = (const float*)d_in[8];
  const float* lwp  = (const float*)d_in[9];
  unsigned short* Abf = (unsigned short*)d_ws;   // 64 KB Abf + 8 KB WgT

  prep_A<<<144, 256, 0, stream>>>(ain, aout, gwp, ogwp, lwp, Abf);
  gcn_main<<<4096, 512, 0, stream>>>(H, Abf, eb, bgp, oebp, obgp, (float*)d_out);
}